// Round 1
// baseline (101.955 us; speedup 1.0000x reference)
//
#include <hip/hip_runtime.h>

// LoKr: out[b, l*64+k] = (1/16) * sum_{m,n} x[b, m*64+n] * w1[l,m] * w2[k,n]
// with w1 = w1_a^T @ w1_b^T (64x64, rank 16), w2 = w2_a^T @ w2_b^T.
// Rank-factored per row:  P = w1_b^T X_b   (16x64, contract m)
//                         Q = P w2_b       (16x16, contract n)
//                         U = Q w2_a       (16x64, contract r2)
//                         Y = w1_a^T-apply (64x64, contract r), scale 1/16
// 163K MACs/row * 8192 rows = 2.7 GFLOP; memory floor 268 MB -> ~42.5 us.

#define WAVES_PER_BLOCK 4
#define ROWS_PER_WAVE 2

__device__ __forceinline__ void lds_fence() {
    // wave-local: drain LDS ops + compiler reorder barrier (no __syncthreads needed;
    // each wave owns its P/Q scratch region)
    asm volatile("s_waitcnt lgkmcnt(0)" ::: "memory");
}

__global__ __launch_bounds__(256) void lokr_kernel(
    const float* __restrict__ x,
    const float* __restrict__ w1_a,   // (16, 64) [r][l]
    const float* __restrict__ w1_b,   // (64, 16) [m][r]
    const float* __restrict__ w2_a,   // (16, 64) [r2][k]
    const float* __restrict__ w2_b,   // (64, 16) [n][r2]
    float* __restrict__ out)
{
    __shared__ __align__(16) float s_w1b[64][16];   // [m][r]
    __shared__ __align__(16) float s_w1aT[64][16];  // [l][r]
    __shared__ __align__(16) float s_w2b[64][16];   // [n][r2]
    __shared__ __align__(16) float s_P[WAVES_PER_BLOCK][16][65];  // padded: bank = (r+n)%32
    __shared__ __align__(16) float s_Q[WAVES_PER_BLOCK][16][16];

    const int tid = threadIdx.x;

    // ---- stage weights into LDS (once per block) ----
    for (int i = tid; i < 1024; i += 256) {
        s_w1b[i >> 4][i & 15] = w1_b[i];
        s_w2b[i >> 4][i & 15] = w2_b[i];
        const int r = i >> 6, l = i & 63;
        s_w1aT[l][r] = w1_a[i];
    }
    __syncthreads();

    const int wave = tid >> 6;
    const int lane = tid & 63;
    const int gw   = blockIdx.x * WAVES_PER_BLOCK + wave;   // 0..4095
    const int b0   = gw * ROWS_PER_WAVE;                    // first of 2 rows

    // hoist w2_a column per lane: w2a[s] = w2_a[s][lane]  (coalesced, once)
    float w2a[16];
#pragma unroll
    for (int s = 0; s < 16; ++s) w2a[s] = w2_a[s * 64 + lane];

    // ---- S1: accP[j][r] = sum_m w1_b[m][r] * x[b0+j][m*64+lane] ----
    float accP[ROWS_PER_WAVE][16];
#pragma unroll
    for (int j = 0; j < ROWS_PER_WAVE; ++j)
#pragma unroll
        for (int r = 0; r < 16; ++r) accP[j][r] = 0.f;

    const float* xb = x + (size_t)b0 * 4096 + lane;
#pragma unroll 8
    for (int m = 0; m < 64; ++m) {
        float xv[ROWS_PER_WAVE];
#pragma unroll
        for (int j = 0; j < ROWS_PER_WAVE; ++j)
            xv[j] = xb[(size_t)j * 4096 + m * 64];          // 256 B/wave, coalesced
#pragma unroll
        for (int r4 = 0; r4 < 4; ++r4) {
            const float4 wv = *(const float4*)&s_w1b[m][r4 * 4];  // wave-uniform broadcast
            const float w0 = wv.x, w1 = wv.y, w2 = wv.z, w3 = wv.w;
#pragma unroll
            for (int j = 0; j < ROWS_PER_WAVE; ++j) {
                accP[j][r4 * 4 + 0] += w0 * xv[j];
                accP[j][r4 * 4 + 1] += w1 * xv[j];
                accP[j][r4 * 4 + 2] += w2 * xv[j];
                accP[j][r4 * 4 + 3] += w3 * xv[j];
            }
        }
    }

    // ---- per-row S2 (Q), S3 (U) through per-wave LDS scratch ----
    float U[ROWS_PER_WAVE][16];
    const int rq = lane >> 2;          // 0..15
    const int s0 = (lane & 3) * 4;     // 0,4,8,12
#pragma unroll
    for (int j = 0; j < ROWS_PER_WAVE; ++j) {
        lds_fence();                                   // prior iter's reads done before overwrite
#pragma unroll
        for (int r = 0; r < 16; ++r) s_P[wave][r][lane] = accP[j][r];
        lds_fence();                                   // P visible wave-wide

        // S2: Q[rq][s0..s0+3] = sum_n P[rq][n] * w2_b[n][s0..s0+3]
        float q0 = 0.f, q1 = 0.f, q2 = 0.f, q3 = 0.f;
#pragma unroll 8
        for (int n = 0; n < 64; ++n) {
            const float pv = s_P[wave][rq][n];         // 16 distinct banks, 4-lane broadcast
            const float4 wv = *(const float4*)&s_w2b[n][s0];
            q0 += pv * wv.x; q1 += pv * wv.y; q2 += pv * wv.z; q3 += pv * wv.w;
        }
        float4 qv4; qv4.x = q0; qv4.y = q1; qv4.z = q2; qv4.w = q3;
        *(float4*)&s_Q[wave][rq][s0] = qv4;
        lds_fence();                                   // Q visible wave-wide

        // S3: U[j][r] = sum_s Q[r][s] * w2a[s]
#pragma unroll
        for (int r = 0; r < 16; ++r) {
            float acc = 0.f;
#pragma unroll
            for (int s4 = 0; s4 < 4; ++s4) {
                const float4 qv = *(const float4*)&s_Q[wave][r][s4 * 4];  // uniform broadcast
                acc += qv.x * w2a[s4 * 4 + 0];
                acc += qv.y * w2a[s4 * 4 + 1];
                acc += qv.z * w2a[s4 * 4 + 2];
                acc += qv.w * w2a[s4 * 4 + 3];
            }
            U[j][r] = acc;
        }
        lds_fence();                                   // S3 reads done before next iter's writes
    }

    // ---- S4: out[b][l*64+lane] = (1/16) * sum_r w1_a[r][l] * U[j][r] ----
    float* op = out + (size_t)b0 * 4096 + lane;
#pragma unroll 4
    for (int l = 0; l < 64; ++l) {
        float y[ROWS_PER_WAVE];
#pragma unroll
        for (int j = 0; j < ROWS_PER_WAVE; ++j) y[j] = 0.f;
#pragma unroll
        for (int r4 = 0; r4 < 4; ++r4) {
            const float4 wv = *(const float4*)&s_w1aT[l][r4 * 4];   // wave-uniform broadcast
            const float w0 = wv.x, w1 = wv.y, w2 = wv.z, w3 = wv.w;
#pragma unroll
            for (int j = 0; j < ROWS_PER_WAVE; ++j) {
                y[j] += w0 * U[j][r4 * 4 + 0];
                y[j] += w1 * U[j][r4 * 4 + 1];
                y[j] += w2 * U[j][r4 * 4 + 2];
                y[j] += w3 * U[j][r4 * 4 + 3];
            }
        }
#pragma unroll
        for (int j = 0; j < ROWS_PER_WAVE; ++j)
            op[(size_t)j * 4096 + l * 64] = y[j] * 0.0625f;        // 256 B/wave, coalesced
    }
}

extern "C" void kernel_launch(void* const* d_in, const int* in_sizes, int n_in,
                              void* d_out, int out_size, void* d_ws, size_t ws_size,
                              hipStream_t stream) {
    const float* x    = (const float*)d_in[0];
    const float* w1_a = (const float*)d_in[1];
    const float* w1_b = (const float*)d_in[2];
    const float* w2_a = (const float*)d_in[3];
    const float* w2_b = (const float*)d_in[4];
    float* out = (float*)d_out;

    // 8192 rows / (4 waves * 2 rows/wave) = 1024 blocks
    dim3 grid(1024), block(256);
    hipLaunchKernelGGL(lokr_kernel, grid, block, 0, stream,
                       x, w1_a, w1_b, w2_a, w2_b, out);
}

// Round 2
// 68.341 us; speedup vs baseline: 1.4919x; 1.4919x over previous
//
#include <hip/hip_runtime.h>

// LoKr: out[b, l*64+k] = (1/16) * sum_{m,n} x[b, m*64+n] * w1[l,m] * w2[k,n]
// Rank-factored per row:  P[r][n] = sum_m w1_b[m][r] x[m][n]   (contract m)
//                         Q[r][s] = sum_n P[r][n]  w2_b[n][s]  (contract n)
//                         U[r][k] = sum_s Q[r][s]  w2_a[s][k]  (contract s)
//                         Y[l][k] = sum_r U[r][k]  w1_a[r][l]  (contract r), x 1/16
// 163K MACs/row; compute floor ~17us, memory floor ~30-42us (x is L3-warm).
// R2: 1 row/wave (8192 waves), 16-deep pipelined S1 loads, VGPR<=128 (4 waves/SIMD).

#define WAVES_PER_BLOCK 4

__device__ __forceinline__ void lds_fence() {
    // wave-local LDS drain + compiler reorder barrier (each wave owns its scratch)
    asm volatile("s_waitcnt lgkmcnt(0)" ::: "memory");
}

__global__ __launch_bounds__(256, 4) void lokr_kernel(
    const float* __restrict__ x,
    const float* __restrict__ w1_a,   // (16, 64) [r][l]
    const float* __restrict__ w1_b,   // (64, 16) [m][r]
    const float* __restrict__ w2_a,   // (16, 64) [s][k]
    const float* __restrict__ w2_b,   // (64, 16) [n][s]
    float* __restrict__ out)
{
    __shared__ __align__(16) float s_w1b[64][16];   // [m][r]
    __shared__ __align__(16) float s_w1aT[64][16];  // [l][r]
    __shared__ __align__(16) float s_w2b[64][16];   // [n][s]
    __shared__ __align__(16) float s_P[WAVES_PER_BLOCK][16][65];  // pad 65: bank=(r+n)%32
    __shared__ __align__(16) float s_Q[WAVES_PER_BLOCK][16][16];

    const int tid = threadIdx.x;

    // ---- stage weights into LDS (once per block) ----
    for (int i = tid; i < 1024; i += 256) {
        s_w1b[i >> 4][i & 15] = w1_b[i];
        s_w2b[i >> 4][i & 15] = w2_b[i];
        const int r = i >> 6, l = i & 63;
        s_w1aT[l][r] = w1_a[i];
    }
    __syncthreads();

    const int wave = tid >> 6;
    const int lane = tid & 63;
    const int b    = blockIdx.x * WAVES_PER_BLOCK + wave;   // 0..8191, one row per wave

    // hoist w2_a column per lane: w2a[s] = w2_a[s][lane]  (coalesced, once)
    float w2a[16];
#pragma unroll
    for (int s = 0; s < 16; ++s) w2a[s] = w2_a[s * 64 + lane];

    // ---- S1: accP[r] = sum_m w1_b[m][r] * x[b][m*64+lane] ----
    // Software pipeline: 16 loads in flight while FMA-ing previous 16.
    float accP[16];
#pragma unroll
    for (int r = 0; r < 16; ++r) accP[r] = 0.f;

    const float* xb = x + (size_t)b * 4096 + lane;

    float xv[16];
#pragma unroll
    for (int i = 0; i < 16; ++i) xv[i] = xb[i * 64];        // group 0 in flight

#pragma unroll
    for (int g = 0; g < 4; ++g) {
        float xn[16];
        if (g < 3) {
#pragma unroll
            for (int i = 0; i < 16; ++i)
                xn[i] = xb[((g + 1) * 16 + i) * 64];        // next group in flight
        }
#pragma unroll
        for (int i = 0; i < 16; ++i) {
            const int m = g * 16 + i;
            const float xvi = xv[i];
#pragma unroll
            for (int r4 = 0; r4 < 4; ++r4) {
                const float4 wv = *(const float4*)&s_w1b[m][r4 * 4];  // uniform broadcast
                accP[r4 * 4 + 0] += wv.x * xvi;
                accP[r4 * 4 + 1] += wv.y * xvi;
                accP[r4 * 4 + 2] += wv.z * xvi;
                accP[r4 * 4 + 3] += wv.w * xvi;
            }
        }
        if (g < 3) {
#pragma unroll
            for (int i = 0; i < 16; ++i) xv[i] = xn[i];     // register rename
        }
    }

    // ---- S2: Q via per-wave LDS scratch (all 64 lanes participate) ----
    const int rq = lane >> 2;          // 0..15
    const int s0 = (lane & 3) * 4;     // 0,4,8,12
#pragma unroll
    for (int r = 0; r < 16; ++r) s_P[wave][r][lane] = accP[r];
    lds_fence();                                   // P visible wave-wide

    float q0 = 0.f, q1 = 0.f, q2 = 0.f, q3 = 0.f;
#pragma unroll 16
    for (int n = 0; n < 64; ++n) {
        const float pv = s_P[wave][rq][n];         // 16 distinct banks, 4-lane broadcast
        const float4 wv = *(const float4*)&s_w2b[n][s0];
        q0 += pv * wv.x; q1 += pv * wv.y; q2 += pv * wv.z; q3 += pv * wv.w;
    }
    float4 qv4; qv4.x = q0; qv4.y = q1; qv4.z = q2; qv4.w = q3;
    *(float4*)&s_Q[wave][rq][s0] = qv4;
    lds_fence();                                   // Q visible wave-wide

    // ---- S3: U[r] = sum_s Q[r][s] * w2a[s] ----
    float U[16];
#pragma unroll
    for (int r = 0; r < 16; ++r) {
        float acc = 0.f;
#pragma unroll
        for (int s4 = 0; s4 < 4; ++s4) {
            const float4 qv = *(const float4*)&s_Q[wave][r][s4 * 4];  // uniform broadcast
            acc += qv.x * w2a[s4 * 4 + 0];
            acc += qv.y * w2a[s4 * 4 + 1];
            acc += qv.z * w2a[s4 * 4 + 2];
            acc += qv.w * w2a[s4 * 4 + 3];
        }
        U[r] = acc;
    }

    // ---- S4: out[b][l*64+lane] = (1/16) * sum_r w1_a[r][l] * U[r] ----
    float* op = out + (size_t)b * 4096 + lane;
#pragma unroll 8
    for (int l = 0; l < 64; ++l) {
        float y = 0.f;
#pragma unroll
        for (int r4 = 0; r4 < 4; ++r4) {
            const float4 wv = *(const float4*)&s_w1aT[l][r4 * 4];   // uniform broadcast
            y += wv.x * U[r4 * 4 + 0];
            y += wv.y * U[r4 * 4 + 1];
            y += wv.z * U[r4 * 4 + 2];
            y += wv.w * U[r4 * 4 + 3];
        }
        op[l * 64] = y * 0.0625f;                  // 256 B/wave, coalesced
    }
}

extern "C" void kernel_launch(void* const* d_in, const int* in_sizes, int n_in,
                              void* d_out, int out_size, void* d_ws, size_t ws_size,
                              hipStream_t stream) {
    const float* x    = (const float*)d_in[0];
    const float* w1_a = (const float*)d_in[1];
    const float* w1_b = (const float*)d_in[2];
    const float* w2_a = (const float*)d_in[3];
    const float* w2_b = (const float*)d_in[4];
    float* out = (float*)d_out;

    // 8192 rows / (4 waves * 1 row/wave) = 2048 blocks
    dim3 grid(2048), block(256);
    hipLaunchKernelGGL(lokr_kernel, grid, block, 0, stream,
                       x, w1_a, w1_b, w2_a, w2_b, out);
}

// Round 3
// 67.452 us; speedup vs baseline: 1.5115x; 1.0132x over previous
//
#include <hip/hip_runtime.h>

// LoKr: out[b, l*64+k] = (1/16) * sum_{m,n} x[b, m*64+n] * w1[l,m] * w2[k,n]
// Rank-factored per row:  P[r][n] = sum_m w1_b[m][r] x[m][n]   (contract m)
//                         Q[r][s] = sum_n P[r][n]  w2_b[n][s]  (contract n)
//                         U[r][k] = sum_s Q[r][s]  w2_a[s][k]  (contract s)
//                         Y[l][k] = sum_r U[r][k]  w1_a[r][l]  (contract r), x 1/16
// R3: weights via scalar path (uniform global reads -> s_load, K$-cached, one
// SGPR operand per FMA). LDS only for cross-lane P/Q scratch (20.7KB/block).
// R2 was LDS-issue-bound: 512 uniform ds_read_b128/wave of weights ~= whole runtime.

#define WAVES_PER_BLOCK 4

__device__ __forceinline__ void lds_fence() {
    // wave-local LDS drain + compiler reorder barrier (each wave owns its scratch)
    asm volatile("s_waitcnt lgkmcnt(0)" ::: "memory");
}

__global__ __launch_bounds__(256, 4) void lokr_kernel(
    const float* __restrict__ x,
    const float* __restrict__ w1_a,   // (16, 64) [r][l]
    const float* __restrict__ w1_b,   // (64, 16) [m][r]
    const float* __restrict__ w2_a,   // (16, 64) [s][k]
    const float* __restrict__ w2_b,   // (64, 16) [n][s]
    float* __restrict__ out)
{
    __shared__ __align__(16) float s_P[WAVES_PER_BLOCK][16][65];  // bank=(r+n)%32, conflict-free
    __shared__ __align__(16) float s_Q[WAVES_PER_BLOCK][16][16];

    const int tid  = threadIdx.x;
    const int wave = tid >> 6;
    const int lane = tid & 63;
    const int b    = blockIdx.x * WAVES_PER_BLOCK + wave;   // one row per wave

    // per-lane w2_a column: w2a[s] = w2_a[s][lane]  (coalesced vector loads, once)
    float w2a[16];
#pragma unroll
    for (int s = 0; s < 16; ++s) w2a[s] = w2_a[s * 64 + lane];

    // ---- S1: accP[r] = sum_m w1_b[m][r] * x[b][m*64+lane] ----
    // x: 16-deep pipelined scalar-dword loads (stride 256B, coalesced per wave).
    // w1_b: thread-invariant address -> scalar loads (SGPR), no LDS, no VALU cost.
    float accP[16];
#pragma unroll
    for (int r = 0; r < 16; ++r) accP[r] = 0.f;

    const float* xb = x + (size_t)b * 4096 + lane;

    float xv[16];
#pragma unroll
    for (int i = 0; i < 16; ++i) xv[i] = xb[i * 64];        // group 0 in flight

#pragma unroll
    for (int g = 0; g < 4; ++g) {
        float xn[16];
        if (g < 3) {
#pragma unroll
            for (int i = 0; i < 16; ++i)
                xn[i] = xb[((g + 1) * 16 + i) * 64];        // next group in flight
        }
#pragma unroll
        for (int i = 0; i < 16; ++i) {
            const int m = g * 16 + i;
            const float xvi = xv[i];
#pragma unroll
            for (int r4 = 0; r4 < 4; ++r4) {
                const float4 wv = *(const float4*)&w1_b[m * 16 + r4 * 4];  // uniform -> s_load
                accP[r4 * 4 + 0] += wv.x * xvi;
                accP[r4 * 4 + 1] += wv.y * xvi;
                accP[r4 * 4 + 2] += wv.z * xvi;
                accP[r4 * 4 + 3] += wv.w * xvi;
            }
        }
        if (g < 3) {
#pragma unroll
            for (int i = 0; i < 16; ++i) xv[i] = xn[i];     // register rename
        }
    }

    // ---- S2: Q[rq][s0..s0+3] via per-wave LDS P scratch ----
    const int rq = lane >> 2;          // 0..15
    const int s0 = (lane & 3) * 4;     // 0,4,8,12
#pragma unroll
    for (int r = 0; r < 16; ++r) s_P[wave][r][lane] = accP[r];   // 2-way bank alias: free
    lds_fence();                                   // P visible wave-wide

    float q0 = 0.f, q1 = 0.f, q2 = 0.f, q3 = 0.f;
#pragma unroll 16
    for (int n = 0; n < 64; ++n) {
        const float pv = s_P[wave][rq][n];         // 16 distinct banks, 4-lane broadcast
        const float4 wv = *(const float4*)&w2_b[n * 16 + s0];  // 64B line/wave, L1-hot
        q0 += pv * wv.x; q1 += pv * wv.y; q2 += pv * wv.z; q3 += pv * wv.w;
    }
    float4 qv4; qv4.x = q0; qv4.y = q1; qv4.z = q2; qv4.w = q3;
    *(float4*)&s_Q[wave][rq][s0] = qv4;
    lds_fence();                                   // Q visible wave-wide

    // ---- S3: U[r] = sum_s Q[r][s] * w2a[s] ----
    float U[16];
#pragma unroll
    for (int r = 0; r < 16; ++r) {
        float acc = 0.f;
#pragma unroll
        for (int s4 = 0; s4 < 4; ++s4) {
            const float4 qv = *(const float4*)&s_Q[wave][r][s4 * 4];  // uniform broadcast
            acc += qv.x * w2a[s4 * 4 + 0];
            acc += qv.y * w2a[s4 * 4 + 1];
            acc += qv.z * w2a[s4 * 4 + 2];
            acc += qv.w * w2a[s4 * 4 + 3];
        }
        U[r] = acc;
    }

    // ---- S4: y[l] = sum_r w1_a[r][l] * U[r]; two 32-wide halves ----
    // w1_a rows are contiguous in l -> uniform float4 reads (s_load), accumulate
    // into 32 per-lane y registers, then coalesced stores.
    float* op = out + (size_t)b * 4096 + lane;
#pragma unroll
    for (int h = 0; h < 2; ++h) {
        float y[32];
#pragma unroll
        for (int l = 0; l < 32; ++l) y[l] = 0.f;
#pragma unroll 4
        for (int r = 0; r < 16; ++r) {
            const float ur = U[r];
            const float* wrow = w1_a + r * 64 + h * 32;     // contiguous, uniform
#pragma unroll
            for (int l4 = 0; l4 < 8; ++l4) {
                const float4 wv = *(const float4*)&wrow[l4 * 4];   // uniform -> s_load
                y[l4 * 4 + 0] += wv.x * ur;
                y[l4 * 4 + 1] += wv.y * ur;
                y[l4 * 4 + 2] += wv.z * ur;
                y[l4 * 4 + 3] += wv.w * ur;
            }
        }
#pragma unroll
        for (int l = 0; l < 32; ++l)
            op[(h * 32 + l) * 64] = y[l] * 0.0625f;         // 256 B/wave, coalesced
    }
}

extern "C" void kernel_launch(void* const* d_in, const int* in_sizes, int n_in,
                              void* d_out, int out_size, void* d_ws, size_t ws_size,
                              hipStream_t stream) {
    const float* x    = (const float*)d_in[0];
    const float* w1_a = (const float*)d_in[1];
    const float* w1_b = (const float*)d_in[2];
    const float* w2_a = (const float*)d_in[3];
    const float* w2_b = (const float*)d_in[4];
    float* out = (float*)d_out;

    // 8192 rows / (4 waves * 1 row/wave) = 2048 blocks
    dim3 grid(2048), block(256);
    hipLaunchKernelGGL(lokr_kernel, grid, block, 0, stream,
                       x, w1_a, w1_b, w2_a, w2_b, out);
}